// Round 10
// baseline (313.544 us; speedup 1.0000x reference)
//
#include <hip/hip_runtime.h>
#include <cstdint>
#include <cstddef>

// GRU cell fused: B=16384, I=H=512.
// ws: X bf16 [16384][1024] @0 (32 MB), Wrz bf16 [1024][1024] @32M (2 MB),
//     Wih bf16 [512][1024] @34M (1 MB).
// gru_fused: BM=128 x BN=64, BK=32, DOUBLE-buffered LDS (2x20KB), one
// __syncthreads per K-step with stage-early/drain-late (m97 schedule),
// 4 blocks/CU.  No raw barriers, no inline-asm waitcnt (de-risked).

typedef __attribute__((ext_vector_type(8))) __bf16 bf16x8;
typedef __attribute__((ext_vector_type(4))) float f32x4;
typedef __attribute__((ext_vector_type(8))) unsigned short u16x8;

__device__ __forceinline__ unsigned short f2bf(float f) {
    unsigned u = __builtin_bit_cast(unsigned, f);
    return (unsigned short)((u + 0x7fffu + ((u >> 16) & 1u)) >> 16);  // RNE
}

__global__ void prep_x(const float* __restrict__ inp, const float* __restrict__ hid,
                       unsigned short* __restrict__ X) {
    int t = blockIdx.x * 256 + threadIdx.x;   // 16384*128 threads
    int b = t >> 7;
    int j = (t & 127) << 3;                   // 0..1016, step 8
    const float* src = (j < 512) ? (inp + (size_t)b * 512 + j)
                                 : (hid + (size_t)b * 512 + (j - 512));
    u16x8 o;
#pragma unroll
    for (int e = 0; e < 8; ++e) o[e] = f2bf(src[e]);
    *reinterpret_cast<u16x8*>(X + (size_t)b * 1024 + j) = o;
}

__global__ void prep_w(const float* __restrict__ Wg, const float* __restrict__ Wi,
                       const float* __restrict__ Wh,
                       unsigned short* __restrict__ Wrz, unsigned short* __restrict__ Wih) {
    int t = blockIdx.x * 256 + threadIdx.x;   // 196608 threads
    if (t < 131072) {                         // W_gate: 1M elements, 8/thread
        const float* src = Wg + (size_t)t * 8;
        u16x8 o;
#pragma unroll
        for (int e = 0; e < 8; ++e) o[e] = f2bf(src[e]);
        *reinterpret_cast<u16x8*>(Wrz + (size_t)t * 8) = o;
    } else {                                  // Wih[n][k] = k<512 ? Wi[n][k] : Wh[n][k-512]
        int u = t - 131072;                   // 512 rows x 128 chunks
        int n = u >> 7;
        int k = (u & 127) << 3;
        const float* src = (k < 512) ? (Wi + (size_t)n * 512 + k)
                                     : (Wh + (size_t)n * 512 + (k - 512));
        u16x8 o;
#pragma unroll
        for (int e = 0; e < 8; ++e) o[e] = f2bf(src[e]);
        *reinterpret_cast<u16x8*>(Wih + (size_t)n * 1024 + k) = o;
    }
}

__device__ __forceinline__ void gload16(const void* g, void* l) {
    __builtin_amdgcn_global_load_lds(
        (const __attribute__((address_space(1))) void*)g,
        (__attribute__((address_space(3))) void*)l, 16, 0, 0);
}

// BK=32 tiles: rows of 32 bf16 (64 B = 4 chunks of 16 B).  Logical chunk ch of
// row r stored at physical chunk (ch ^ ((r>>1)&3)).  Per 16-lane read phase:
// 2 lanes/bank (free).  Staged via pre-swizzled global source (involution).
__device__ __forceinline__ bf16x8 ldfrag32(const unsigned short* base, int row, int c0) {
    const char* p = (const char*)base + row * 64 + ((c0 ^ ((row >> 1) & 3)) << 4);
    return *reinterpret_cast<const bf16x8*>(p);
}

__global__ __launch_bounds__(256, 4) void gru_fused(
        const unsigned short* __restrict__ X,    // [16384][1024] bf16
        const unsigned short* __restrict__ Wr,   // [512][1024] bf16
        const unsigned short* __restrict__ Wz,   // [512][1024] bf16
        const unsigned short* __restrict__ Wih,  // [512][1024] bf16
        const float* __restrict__ hid,           // [16384][512]
        const float* __restrict__ bgate,         // [1024]
        const float* __restrict__ bi,            // [512]
        const float* __restrict__ bh,            // [512]
        float* __restrict__ out) {               // [16384][512]
    // Per buffer (20 KB): X[128x32] @0, R[64x32] @8KB, Z @12KB, W @16KB.
    __shared__ unsigned short lds[2][10240];     // 40 KB -> 4 blocks/CU

    const int tid = threadIdx.x;
    const int lane = tid & 63;
    const int wid = tid >> 6;
    const int wm = wid >> 1, wn = wid & 1;       // 2x2 waves; wave = 64x32 per gate
    const int bid = blockIdx.x;
    const int bn = bid & 7;                      // col tile -> XCD (weights L2-resident)
    const int bm = bid >> 3;                     // 128 row tiles

    // --- staging source (pre-swizzled): thread covers chunk (row=tid>>2, c=tid&3),
    //     storing logical chunk lc = (tid&3) ^ ((tid>>3)&3).
    const int srow = tid >> 2;                   // 0..63
    const int lc = (tid & 3) ^ ((tid >> 3) & 3);
    const char* gX0 = (const char*)X   + ((size_t)(bm * 128 + srow) * 1024 + lc * 8) * 2;
    const char* gX1 = gX0 + 64 * 2048;           // rows 64..127 (same lc: +64 rows keeps (r>>1)&3)
    const char* gR  = (const char*)Wr  + ((size_t)(bn * 64 + srow) * 1024 + lc * 8) * 2;
    const char* gZ  = (const char*)Wz  + ((size_t)(bn * 64 + srow) * 1024 + lc * 8) * 2;
    const char* gW  = (const char*)Wih + ((size_t)(bn * 64 + srow) * 1024 + lc * 8) * 2;

    f32x4 accR[4][2], accZ[4][2], accI[4][2], accH[4][2];
#pragma unroll
    for (int i = 0; i < 4; ++i)
#pragma unroll
        for (int j = 0; j < 2; ++j) {
            accR[i][j] = (f32x4){0.f, 0.f, 0.f, 0.f};
            accZ[i][j] = (f32x4){0.f, 0.f, 0.f, 0.f};
            accI[i][j] = (f32x4){0.f, 0.f, 0.f, 0.f};
            accH[i][j] = (f32x4){0.f, 0.f, 0.f, 0.f};
        }

    const int ra = wm * 64 + (lane & 15);        // A-frag base row
    const int rb = wn * 32 + (lane & 15);        // B-frag base row (out col)
    const int c0 = lane >> 4;                    // k-chunk 0..3 (k = c0*8..c0*8+7)

    // 5 global_load_lds per thread per tile; LDS dest is wave-linear.
#define STAGE(t, b) {                                                  \
        gload16(gX0 + (t) * 64, (char*)lds[b] + tid * 16);             \
        gload16(gX1 + (t) * 64, (char*)lds[b] + 4096 + tid * 16);      \
        gload16(gR  + (t) * 64, (char*)lds[b] + 8192 + tid * 16);      \
        gload16(gZ  + (t) * 64, (char*)lds[b] + 12288 + tid * 16);     \
        gload16(gW  + (t) * 64, (char*)lds[b] + 16384 + tid * 16); }

#define MFMA8(ACC, B0, B1)                                                            \
    ACC[0][0] = __builtin_amdgcn_mfma_f32_16x16x32_bf16(a0, B0, ACC[0][0], 0, 0, 0); \
    ACC[1][0] = __builtin_amdgcn_mfma_f32_16x16x32_bf16(a1, B0, ACC[1][0], 0, 0, 0); \
    ACC[2][0] = __builtin_amdgcn_mfma_f32_16x16x32_bf16(a2, B0, ACC[2][0], 0, 0, 0); \
    ACC[3][0] = __builtin_amdgcn_mfma_f32_16x16x32_bf16(a3, B0, ACC[3][0], 0, 0, 0); \
    ACC[0][1] = __builtin_amdgcn_mfma_f32_16x16x32_bf16(a0, B1, ACC[0][1], 0, 0, 0); \
    ACC[1][1] = __builtin_amdgcn_mfma_f32_16x16x32_bf16(a1, B1, ACC[1][1], 0, 0, 0); \
    ACC[2][1] = __builtin_amdgcn_mfma_f32_16x16x32_bf16(a2, B1, ACC[2][1], 0, 0, 0); \
    ACC[3][1] = __builtin_amdgcn_mfma_f32_16x16x32_bf16(a3, B1, ACC[3][1], 0, 0, 0);

#define COMPUTE(b, ACC3) {                                             \
        const unsigned short* bp = lds[b];                             \
        bf16x8 a0 = ldfrag32(bp, ra,      c0);                         \
        bf16x8 a1 = ldfrag32(bp, ra + 16, c0);                         \
        bf16x8 a2 = ldfrag32(bp, ra + 32, c0);                         \
        bf16x8 a3 = ldfrag32(bp, ra + 48, c0);                         \
        bf16x8 b0 = ldfrag32(bp + 4096, rb, c0);                       \
        bf16x8 b1 = ldfrag32(bp + 4096, rb + 16, c0);                  \
        MFMA8(accR, b0, b1)                                            \
        b0 = ldfrag32(bp + 6144, rb, c0);                              \
        b1 = ldfrag32(bp + 6144, rb + 16, c0);                         \
        MFMA8(accZ, b0, b1)                                            \
        b0 = ldfrag32(bp + 8192, rb, c0);                              \
        b1 = ldfrag32(bp + 8192, rb + 16, c0);                         \
        MFMA8(ACC3, b0, b1) }

    // --- prologue: stage tile 0 ---
    STAGE(0, 0)
    __syncthreads();

    // --- main loop: stage t+1 early, compute t, sync (drain) late ---
#pragma unroll 2
    for (int t = 0; t < 16; ++t) {
        STAGE(t + 1, (t + 1) & 1)              // loads in flight during compute
        COMPUTE(t & 1, accI)
        __syncthreads();                       // drains vmcnt: tile t+1 landed
    }
#pragma unroll 2
    for (int t = 16; t < 32; ++t) {
        if (t < 31) STAGE(t + 1, (t + 1) & 1)
        COMPUTE(t & 1, accH)
        __syncthreads();
    }
#undef COMPUTE
#undef MFMA8
#undef STAGE

    // --- fused GRU epilogue ---
    const int colb = bn * 64 + wn * 32 + (lane & 15);
    const int rowb = bm * 128 + wm * 64 + ((lane >> 4) << 2);
#pragma unroll
    for (int ni = 0; ni < 2; ++ni) {
        const int n = colb + ni * 16;
        const float bgr = bgate[n];
        const float bgz = bgate[512 + n];
        const float bii = bi[n];
        const float bhh = bh[n];
#pragma unroll
        for (int mi = 0; mi < 4; ++mi) {
#pragma unroll
            for (int r = 0; r < 4; ++r) {
                const int m = rowb + mi * 16 + r;
                const size_t off = (size_t)m * 512 + n;
                float rg = accR[mi][ni][r] + bgr;
                rg = 1.f / (1.f + __expf(-rg));
                float zg = accZ[mi][ni][r] + bgz;
                zg = 1.f / (1.f + __expf(-zg));
                float x = accI[mi][ni][r] + bii + rg * (accH[mi][ni][r] + bhh);
                x = fminf(fmaxf(x, -15.f), 15.f);
                const float e = __expf(2.f * x);
                const float ng = (e - 1.f) / (e + 1.f);   // tanh(x)
                out[off] = ng + zg * (hid[off] - ng);     // (1-z)*n + z*h
            }
        }
    }
}

extern "C" void kernel_launch(void* const* d_in, const int* in_sizes, int n_in,
                              void* d_out, int out_size, void* d_ws, size_t ws_size,
                              hipStream_t stream) {
    const float* inp = (const float*)d_in[0];
    const float* hid = (const float*)d_in[1];
    const float* Wg  = (const float*)d_in[2];
    const float* bg  = (const float*)d_in[3];
    const float* Wi  = (const float*)d_in[4];
    const float* bi  = (const float*)d_in[5];
    const float* Wh  = (const float*)d_in[6];
    const float* bh  = (const float*)d_in[7];
    float* out = (float*)d_out;

    unsigned short* X   = (unsigned short*)d_ws;
    unsigned short* Wrz = (unsigned short*)((char*)d_ws + 33554432);
    unsigned short* Wih = (unsigned short*)((char*)d_ws + 33554432 + 2097152);

    prep_x<<<8192, 256, 0, stream>>>(inp, hid, X);
    prep_w<<<768, 256, 0, stream>>>(Wg, Wi, Wh, Wrz, Wih);
    gru_fused<<<1024, 256, 0, stream>>>(X, Wrz, Wrz + 512 * 1024, Wih,
                                        hid, bg, bi, bh, out);
}

// Round 11
// 185.370 us; speedup vs baseline: 1.6915x; 1.6915x over previous
//
#include <hip/hip_runtime.h>
#include <cstdint>
#include <cstddef>

// GRU cell fused: B=16384, I=H=512.
// ws: X bf16 [16384][1024] @0 (32 MB), Wrz bf16 [1024][1024] @32M (2 MB),
//     Wih bf16 [512][1024] @34M (1 MB).
// gru_fused: BM=128 x BN=64, BK=32, double-buffered LDS (2x20KB), one
// __syncthreads per K-step, stage-early/drain-late.
// Round 10 lesson: __launch_bounds__(256,4) capped regs at 128/wave ->
// accumulator spill (345 MB scratch writes, 10% MfmaUtil). Must be (256,2).

typedef __attribute__((ext_vector_type(8))) __bf16 bf16x8;
typedef __attribute__((ext_vector_type(4))) float f32x4;
typedef __attribute__((ext_vector_type(8))) unsigned short u16x8;

__device__ __forceinline__ unsigned short f2bf(float f) {
    unsigned u = __builtin_bit_cast(unsigned, f);
    return (unsigned short)((u + 0x7fffu + ((u >> 16) & 1u)) >> 16);  // RNE
}

__global__ void prep_x(const float* __restrict__ inp, const float* __restrict__ hid,
                       unsigned short* __restrict__ X) {
    int t = blockIdx.x * 256 + threadIdx.x;   // 16384*128 threads
    int b = t >> 7;
    int j = (t & 127) << 3;                   // 0..1016, step 8
    const float* src = (j < 512) ? (inp + (size_t)b * 512 + j)
                                 : (hid + (size_t)b * 512 + (j - 512));
    u16x8 o;
#pragma unroll
    for (int e = 0; e < 8; ++e) o[e] = f2bf(src[e]);
    *reinterpret_cast<u16x8*>(X + (size_t)b * 1024 + j) = o;
}

__global__ void prep_w(const float* __restrict__ Wg, const float* __restrict__ Wi,
                       const float* __restrict__ Wh,
                       unsigned short* __restrict__ Wrz, unsigned short* __restrict__ Wih) {
    int t = blockIdx.x * 256 + threadIdx.x;   // 196608 threads
    if (t < 131072) {                         // W_gate: 1M elements, 8/thread
        const float* src = Wg + (size_t)t * 8;
        u16x8 o;
#pragma unroll
        for (int e = 0; e < 8; ++e) o[e] = f2bf(src[e]);
        *reinterpret_cast<u16x8*>(Wrz + (size_t)t * 8) = o;
    } else {                                  // Wih[n][k] = k<512 ? Wi[n][k] : Wh[n][k-512]
        int u = t - 131072;                   // 512 rows x 128 chunks
        int n = u >> 7;
        int k = (u & 127) << 3;
        const float* src = (k < 512) ? (Wi + (size_t)n * 512 + k)
                                     : (Wh + (size_t)n * 512 + (k - 512));
        u16x8 o;
#pragma unroll
        for (int e = 0; e < 8; ++e) o[e] = f2bf(src[e]);
        *reinterpret_cast<u16x8*>(Wih + (size_t)n * 1024 + k) = o;
    }
}

__device__ __forceinline__ void gload16(const void* g, void* l) {
    __builtin_amdgcn_global_load_lds(
        (const __attribute__((address_space(1))) void*)g,
        (__attribute__((address_space(3))) void*)l, 16, 0, 0);
}

// BK=32 tiles: rows of 32 bf16 (64 B = 4 chunks of 16 B).  Logical chunk ch of
// row r stored at physical chunk (ch ^ ((r>>1)&3)).  Per 16-lane read phase:
// 2 lanes/bank (free).  Staged via pre-swizzled global source (involution).
__device__ __forceinline__ bf16x8 ldfrag32(const unsigned short* base, int row, int c0) {
    const char* p = (const char*)base + row * 64 + ((c0 ^ ((row >> 1) & 3)) << 4);
    return *reinterpret_cast<const bf16x8*>(p);
}

__global__ __launch_bounds__(256, 2) void gru_fused(
        const unsigned short* __restrict__ X,    // [16384][1024] bf16
        const unsigned short* __restrict__ Wr,   // [512][1024] bf16
        const unsigned short* __restrict__ Wz,   // [512][1024] bf16
        const unsigned short* __restrict__ Wih,  // [512][1024] bf16
        const float* __restrict__ hid,           // [16384][512]
        const float* __restrict__ bgate,         // [1024]
        const float* __restrict__ bi,            // [512]
        const float* __restrict__ bh,            // [512]
        float* __restrict__ out) {               // [16384][512]
    // Per buffer (20 KB): X[128x32] @0, R[64x32] @8KB, Z @12KB, W @16KB.
    __shared__ unsigned short lds[2][10240];     // 40 KB

    const int tid = threadIdx.x;
    const int lane = tid & 63;
    const int wid = tid >> 6;
    const int wm = wid >> 1, wn = wid & 1;       // 2x2 waves; wave = 64x32 per gate
    const int bid = blockIdx.x;
    const int bn = bid & 7;                      // col tile -> XCD (weights L2-resident)
    const int bm = bid >> 3;                     // 128 row tiles

    // --- staging source (pre-swizzled): thread covers chunk (row=tid>>2, c=tid&3),
    //     storing logical chunk lc = (tid&3) ^ ((tid>>3)&3).
    const int srow = tid >> 2;                   // 0..63
    const int lc = (tid & 3) ^ ((tid >> 3) & 3);
    const char* gX0 = (const char*)X   + ((size_t)(bm * 128 + srow) * 1024 + lc * 8) * 2;
    const char* gX1 = gX0 + 64 * 2048;           // rows 64..127 (same lc)
    const char* gR  = (const char*)Wr  + ((size_t)(bn * 64 + srow) * 1024 + lc * 8) * 2;
    const char* gZ  = (const char*)Wz  + ((size_t)(bn * 64 + srow) * 1024 + lc * 8) * 2;
    const char* gW  = (const char*)Wih + ((size_t)(bn * 64 + srow) * 1024 + lc * 8) * 2;

    f32x4 accR[4][2], accZ[4][2], accI[4][2], accH[4][2];
#pragma unroll
    for (int i = 0; i < 4; ++i)
#pragma unroll
        for (int j = 0; j < 2; ++j) {
            accR[i][j] = (f32x4){0.f, 0.f, 0.f, 0.f};
            accZ[i][j] = (f32x4){0.f, 0.f, 0.f, 0.f};
            accI[i][j] = (f32x4){0.f, 0.f, 0.f, 0.f};
            accH[i][j] = (f32x4){0.f, 0.f, 0.f, 0.f};
        }

    const int ra = wm * 64 + (lane & 15);        // A-frag base row
    const int rb = wn * 32 + (lane & 15);        // B-frag base row (out col)
    const int c0 = lane >> 4;                    // k-chunk 0..3 (k = c0*8..c0*8+7)

    // 5 global_load_lds per thread per tile; LDS dest is wave-linear.
#define STAGE(t, b) {                                                  \
        gload16(gX0 + (t) * 64, (char*)lds[b] + tid * 16);             \
        gload16(gX1 + (t) * 64, (char*)lds[b] + 4096 + tid * 16);      \
        gload16(gR  + (t) * 64, (char*)lds[b] + 8192 + tid * 16);      \
        gload16(gZ  + (t) * 64, (char*)lds[b] + 12288 + tid * 16);     \
        gload16(gW  + (t) * 64, (char*)lds[b] + 16384 + tid * 16); }

#define MFMA8(ACC, B0, B1)                                                            \
    ACC[0][0] = __builtin_amdgcn_mfma_f32_16x16x32_bf16(a0, B0, ACC[0][0], 0, 0, 0); \
    ACC[1][0] = __builtin_amdgcn_mfma_f32_16x16x32_bf16(a1, B0, ACC[1][0], 0, 0, 0); \
    ACC[2][0] = __builtin_amdgcn_mfma_f32_16x16x32_bf16(a2, B0, ACC[2][0], 0, 0, 0); \
    ACC[3][0] = __builtin_amdgcn_mfma_f32_16x16x32_bf16(a3, B0, ACC[3][0], 0, 0, 0); \
    ACC[0][1] = __builtin_amdgcn_mfma_f32_16x16x32_bf16(a0, B1, ACC[0][1], 0, 0, 0); \
    ACC[1][1] = __builtin_amdgcn_mfma_f32_16x16x32_bf16(a1, B1, ACC[1][1], 0, 0, 0); \
    ACC[2][1] = __builtin_amdgcn_mfma_f32_16x16x32_bf16(a2, B1, ACC[2][1], 0, 0, 0); \
    ACC[3][1] = __builtin_amdgcn_mfma_f32_16x16x32_bf16(a3, B1, ACC[3][1], 0, 0, 0);

#define COMPUTE(b, ACC3) {                                             \
        const unsigned short* bp = lds[b];                             \
        bf16x8 a0 = ldfrag32(bp, ra,      c0);                         \
        bf16x8 a1 = ldfrag32(bp, ra + 16, c0);                         \
        bf16x8 a2 = ldfrag32(bp, ra + 32, c0);                         \
        bf16x8 a3 = ldfrag32(bp, ra + 48, c0);                         \
        bf16x8 b0 = ldfrag32(bp + 4096, rb, c0);                       \
        bf16x8 b1 = ldfrag32(bp + 4096, rb + 16, c0);                  \
        MFMA8(accR, b0, b1)                                            \
        b0 = ldfrag32(bp + 6144, rb, c0);                              \
        b1 = ldfrag32(bp + 6144, rb + 16, c0);                         \
        MFMA8(accZ, b0, b1)                                            \
        b0 = ldfrag32(bp + 8192, rb, c0);                              \
        b1 = ldfrag32(bp + 8192, rb + 16, c0);                         \
        MFMA8(ACC3, b0, b1) }

    // --- prologue: stage tile 0 ---
    STAGE(0, 0)
    __syncthreads();

    // --- main loop: stage t+1 early, compute t, sync (drain) late ---
#pragma unroll 2
    for (int t = 0; t < 16; ++t) {
        STAGE(t + 1, (t + 1) & 1)              // loads in flight during compute
        COMPUTE(t & 1, accI)
        __syncthreads();                       // drains vmcnt: tile t+1 landed
    }
#pragma unroll 2
    for (int t = 16; t < 32; ++t) {
        if (t < 31) STAGE(t + 1, (t + 1) & 1)
        COMPUTE(t & 1, accH)
        __syncthreads();
    }
#undef COMPUTE
#undef MFMA8
#undef STAGE

    // --- fused GRU epilogue ---
    const int colb = bn * 64 + wn * 32 + (lane & 15);
    const int rowb = bm * 128 + wm * 64 + ((lane >> 4) << 2);
#pragma unroll
    for (int ni = 0; ni < 2; ++ni) {
        const int n = colb + ni * 16;
        const float bgr = bgate[n];
        const float bgz = bgate[512 + n];
        const float bii = bi[n];
        const float bhh = bh[n];
#pragma unroll
        for (int mi = 0; mi < 4; ++mi) {
#pragma unroll
            for (int r = 0; r < 4; ++r) {
                const int m = rowb + mi * 16 + r;
                const size_t off = (size_t)m * 512 + n;
                float rg = accR[mi][ni][r] + bgr;
                rg = 1.f / (1.f + __expf(-rg));
                float zg = accZ[mi][ni][r] + bgz;
                zg = 1.f / (1.f + __expf(-zg));
                float x = accI[mi][ni][r] + bii + rg * (accH[mi][ni][r] + bhh);
                x = fminf(fmaxf(x, -15.f), 15.f);
                const float e = __expf(2.f * x);
                const float ng = (e - 1.f) / (e + 1.f);   // tanh(x)
                out[off] = ng + zg * (hid[off] - ng);     // (1-z)*n + z*h
            }
        }
    }
}

extern "C" void kernel_launch(void* const* d_in, const int* in_sizes, int n_in,
                              void* d_out, int out_size, void* d_ws, size_t ws_size,
                              hipStream_t stream) {
    const float* inp = (const float*)d_in[0];
    const float* hid = (const float*)d_in[1];
    const float* Wg  = (const float*)d_in[2];
    const float* bg  = (const float*)d_in[3];
    const float* Wi  = (const float*)d_in[4];
    const float* bi  = (const float*)d_in[5];
    const float* Wh  = (const float*)d_in[6];
    const float* bh  = (const float*)d_in[7];
    float* out = (float*)d_out;

    unsigned short* X   = (unsigned short*)d_ws;
    unsigned short* Wrz = (unsigned short*)((char*)d_ws + 33554432);
    unsigned short* Wih = (unsigned short*)((char*)d_ws + 33554432 + 2097152);

    prep_x<<<8192, 256, 0, stream>>>(inp, hid, X);
    prep_w<<<768, 256, 0, stream>>>(Wg, Wi, Wh, Wrz, Wih);
    gru_fused<<<1024, 256, 0, stream>>>(X, Wrz, Wrz + 512 * 1024, Wih,
                                        hid, bg, bi, bh, out);
}